// Round 5
// baseline (227.036 us; speedup 1.0000x reference)
//
#include <hip/hip_runtime.h>

#define N_NODES 20000
#define N_EDGES 640000
#define F 128
#define CAP 128   // max in-degree; deg ~ Binomial(640K, 1/20K), P(deg>=128) ~ 1e-37
#define ROWS 32   // nodes per block

// HISTORY:
//  r2: fused gemm2+proj spilled under default 64-VGPR cap (1.04 GB scratch).
//  r3: launch_bounds(256) still spilled (VGPR=256, 565 MB) -> de-fused in r4:
//      218 us, no spill anywhere. r5: fuse AGGREGATION into the GEMM (gather
//      straight into the LDS tile; float4 x 2-rows-per-wave gather) and drop
//      the aggr intermediate entirely.

// ---------------------------------------------------------------------------
// Single-pass bucket build: bucket[d*CAP + k] = k-th src with dst==d.
// ---------------------------------------------------------------------------
__global__ __launch_bounds__(256)
void bucket_kernel(const int* __restrict__ src, const int* __restrict__ dst,
                   int* __restrict__ cnt, int* __restrict__ bucket) {
    int e = blockIdx.x * blockDim.x + threadIdx.x;
    if (e >= N_EDGES) return;
    int d = dst[e];
    int pos = atomicAdd(&cnt[d], 1);
    if (pos < CAP) bucket[(size_t)d * CAP + pos] = src[e];
}

// ---------------------------------------------------------------------------
// Fused layer: out[32 rows] = relu(mean_agg(feat)[32 rows] @ W + b).
// Phase 1 (gather): wave w aggregates nodes w*8..w*8+7. Lane layout:
//   half = lane>>5 selects even/odd neighbor of a pair, sub = lane&31 is the
//   float4 column. Each gather instruction moves TWO 512B rows (1 KB). 8
//   gathers in flight per wave. Butterfly shfl combines halves; lanes 0-31
//   write the mean as float4 into the LDS tile.
// Phase 2 (GEMM): proven 44-VGPR 32x128 @ 128x128 micro-tiled loop.
// ---------------------------------------------------------------------------
__global__ __launch_bounds__(256)
void fused_layer_kernel(const float* __restrict__ feat, const int* __restrict__ cnt,
                        const int* __restrict__ bucket, const float* __restrict__ W,
                        const float* __restrict__ b, float* __restrict__ out) {
    __shared__ float As[ROWS][F + 4];
    int tid  = threadIdx.x;
    int wave = tid >> 6;
    int lane = tid & 63;
    int half = lane >> 5;
    int sub  = lane & 31;
    int row0 = blockIdx.x * ROWS;

    const float4* f4 = (const float4*)feat;

    for (int t = 0; t < 8; ++t) {
        int nl   = wave * 8 + t;
        int node = row0 + nl;
        int deg  = cnt[node];
        const int* lst = bucket + (size_t)node * CAP;
        float4 acc; acc.x = acc.y = acc.z = acc.w = 0.f;
        int j = 0;
        for (; j + 16 <= deg; j += 16) {   // 16 neighbors = 8 pair-gathers in flight
            int4 ia = *(const int4*)(lst + j);
            int4 ib = *(const int4*)(lst + j + 4);
            int4 ic = *(const int4*)(lst + j + 8);
            int4 id = *(const int4*)(lst + j + 12);
            int i0 = half ? ia.y : ia.x;
            int i1 = half ? ia.w : ia.z;
            int i2 = half ? ib.y : ib.x;
            int i3 = half ? ib.w : ib.z;
            int i4 = half ? ic.y : ic.x;
            int i5 = half ? ic.w : ic.z;
            int i6 = half ? id.y : id.x;
            int i7 = half ? id.w : id.z;
            float4 v0 = f4[(size_t)i0 * 32 + sub];
            float4 v1 = f4[(size_t)i1 * 32 + sub];
            float4 v2 = f4[(size_t)i2 * 32 + sub];
            float4 v3 = f4[(size_t)i3 * 32 + sub];
            float4 v4 = f4[(size_t)i4 * 32 + sub];
            float4 v5 = f4[(size_t)i5 * 32 + sub];
            float4 v6 = f4[(size_t)i6 * 32 + sub];
            float4 v7 = f4[(size_t)i7 * 32 + sub];
            acc.x += ((v0.x + v1.x) + (v2.x + v3.x)) + ((v4.x + v5.x) + (v6.x + v7.x));
            acc.y += ((v0.y + v1.y) + (v2.y + v3.y)) + ((v4.y + v5.y) + (v6.y + v7.y));
            acc.z += ((v0.z + v1.z) + (v2.z + v3.z)) + ((v4.z + v5.z) + (v6.z + v7.z));
            acc.w += ((v0.w + v1.w) + (v2.w + v3.w)) + ((v4.w + v5.w) + (v6.w + v7.w));
        }
        for (; j + 2 <= deg; j += 2) {     // pair tail
            int2 ii = *(const int2*)(lst + j);
            int idx = half ? ii.y : ii.x;
            float4 v = f4[(size_t)idx * 32 + sub];
            acc.x += v.x; acc.y += v.y; acc.z += v.z; acc.w += v.w;
        }
        if (j < deg && half == 0) {        // odd single tail (half-0 lanes only)
            float4 v = f4[(size_t)lst[j] * 32 + sub];
            acc.x += v.x; acc.y += v.y; acc.z += v.z; acc.w += v.w;
        }
        // combine even/odd halves (butterfly across lane^32)
        acc.x += __shfl(acc.x, lane ^ 32);
        acc.y += __shfl(acc.y, lane ^ 32);
        acc.z += __shfl(acc.z, lane ^ 32);
        acc.w += __shfl(acc.w, lane ^ 32);
        if (half == 0) {
            float inv = 1.0f / fmaxf((float)deg, 1.0f);
            float4 o; o.x = acc.x * inv; o.y = acc.y * inv; o.z = acc.z * inv; o.w = acc.w * inv;
            *(float4*)&As[nl][sub * 4] = o;
        }
    }
    __syncthreads();

    // ---- GEMM phase (proven no-spill structure) ----
    int tx = tid & 31, ty = tid >> 5;
    int c0 = tx * 4, r0 = ty * 4;
    float acc2[4][4] = {};

    for (int k = 0; k < F; k += 4) {
        float4 a4[4];
#pragma unroll
        for (int i = 0; i < 4; ++i) a4[i] = *(const float4*)&As[r0 + i][k];
#pragma unroll
        for (int u = 0; u < 4; ++u) {
            float4 w = *(const float4*)(W + (size_t)(k + u) * F + c0);
#pragma unroll
            for (int i = 0; i < 4; ++i) {
                float a = (u == 0) ? a4[i].x : (u == 1) ? a4[i].y : (u == 2) ? a4[i].z : a4[i].w;
                acc2[i][0] += a * w.x;
                acc2[i][1] += a * w.y;
                acc2[i][2] += a * w.z;
                acc2[i][3] += a * w.w;
            }
        }
    }

    float4 bias = *(const float4*)(b + c0);
#pragma unroll
    for (int i = 0; i < 4; ++i) {
        float4 o;
        o.x = fmaxf(acc2[i][0] + bias.x, 0.f);
        o.y = fmaxf(acc2[i][1] + bias.y, 0.f);
        o.z = fmaxf(acc2[i][2] + bias.z, 0.f);
        o.w = fmaxf(acc2[i][3] + bias.w, 0.f);
        *(float4*)(out + (size_t)(row0 + r0 + i) * F + c0) = o;
    }
}

// ---------------------------------------------------------------------------
// out[N x 2] = h[N x 128] @ W3[128 x 2] + b3. One wave per node, shuffle
// reduce. No relu.
// ---------------------------------------------------------------------------
__global__ __launch_bounds__(256)
void final_kernel(const float* __restrict__ h, const float* __restrict__ W3,
                  const float* __restrict__ b3, float* __restrict__ out) {
    int wid  = (blockIdx.x * blockDim.x + threadIdx.x) >> 6;
    int lane = threadIdx.x & 63;
    if (wid >= N_NODES) return;
    float2 v = ((const float2*)h)[(size_t)wid * 64 + lane];
    float4 w = ((const float4*)W3)[lane];
    float a0 = v.x * w.x + v.y * w.z;
    float a1 = v.x * w.y + v.y * w.w;
#pragma unroll
    for (int off = 32; off > 0; off >>= 1) {
        a0 += __shfl_down(a0, off);
        a1 += __shfl_down(a1, off);
    }
    if (lane == 0) {
        out[(size_t)wid * 2]     = a0 + b3[0];
        out[(size_t)wid * 2 + 1] = a1 + b3[1];
    }
}

// ---------------------------------------------------------------------------
extern "C" void kernel_launch(void* const* d_in, const int* in_sizes, int n_in,
                              void* d_out, int out_size, void* d_ws, size_t ws_size,
                              hipStream_t stream) {
    const float* x   = (const float*)d_in[0];
    const int*   ei  = (const int*)d_in[1];
    const int*   src = ei;
    const int*   dst = ei + N_EDGES;
    const float* W1 = (const float*)d_in[2];
    const float* b1 = (const float*)d_in[3];
    const float* W2 = (const float*)d_in[4];
    const float* b2 = (const float*)d_in[5];
    const float* W3 = (const float*)d_in[6];
    const float* b3 = (const float*)d_in[7];
    float* out = (float*)d_out;

    char* base = (char*)d_ws;
    size_t off = 0;
    auto take = [&](size_t bytes) -> char* {
        char* p = base + off;
        off += (bytes + 255) & ~(size_t)255;
        return p;
    };
    int*   cnt    = (int*)  take(N_NODES * sizeof(int));
    int*   bucket = (int*)  take((size_t)N_NODES * CAP * sizeof(int));
    float* h1     = (float*)take((size_t)N_NODES * F * sizeof(float));
    float* h2     = (float*)take((size_t)N_NODES * F * sizeof(float));

    hipMemsetAsync(cnt, 0, N_NODES * sizeof(int), stream);
    bucket_kernel<<<(N_EDGES + 255) / 256, 256, 0, stream>>>(src, dst, cnt, bucket);

    // layer 1: h1 = relu(mean(x) @ W1 + b1)       (fused gather+GEMM)
    fused_layer_kernel<<<N_NODES / ROWS, 256, 0, stream>>>(x, cnt, bucket, W1, b1, h1);
    // layer 2: h2 = relu(mean(h1) @ W2 + b2)      (must not be in-place: gather reads all rows)
    fused_layer_kernel<<<N_NODES / ROWS, 256, 0, stream>>>(h1, cnt, bucket, W2, b2, h2);
    // output projection
    final_kernel<<<(N_NODES * 64 + 255) / 256, 256, 0, stream>>>(h2, W3, b3, out);
}

// Round 6
// 215.194 us; speedup vs baseline: 1.0550x; 1.0550x over previous
//
#include <hip/hip_runtime.h>

#define N_NODES 20000
#define N_EDGES 640000
#define F 128
#define CAP 128   // max in-degree; deg ~ Binomial(640K, 1/20K), P(deg>=128) ~ 1e-37

// HISTORY:
//  r2/r3: fused GEMM+proj epilogue spilled (64-cap / even at 256 VGPR). De-fused r4: 218 us.
//  r5: gather fused INTO gemm tile -> grid 625 blocks, occupancy 22.6%, latency-bound, 227 us.
//  r6: linearity of mean: mean(x)@W == mean(x@W). GEMM first (dense), then a
//      standalone one-wave-per-node gather (5000 blocks -> full occupancy) with
//      bias+relu in the epilogue; last layer's 128->2 projection also fused into
//      the gather epilogue (small, unlike the r2 epilogue that spilled).

// ---------------------------------------------------------------------------
__global__ __launch_bounds__(256)
void bucket_kernel(const int* __restrict__ src, const int* __restrict__ dst,
                   int* __restrict__ cnt, int* __restrict__ bucket) {
    int e = blockIdx.x * blockDim.x + threadIdx.x;
    if (e >= N_EDGES) return;
    int d = dst[e];
    int pos = atomicAdd(&cnt[d], 1);
    if (pos < CAP) bucket[(size_t)d * CAP + pos] = src[e];
}

// ---------------------------------------------------------------------------
// Plain GEMM: C[Mx128] = A[Mx128] @ W[128x128]. Proven 44-VGPR structure.
// ---------------------------------------------------------------------------
__global__ __launch_bounds__(256)
void gemm_kernel(const float* __restrict__ A, const float* __restrict__ W,
                 float* __restrict__ C) {
    __shared__ float As[32][F + 4];
    int tid  = threadIdx.x;
    int row0 = blockIdx.x * 32;

    const float4* A4 = (const float4*)(A + (size_t)row0 * F);
    for (int i = tid; i < 32 * 32; i += 256) {
        float4 v = A4[i];
        int r = i >> 5, c4 = (i & 31) * 4;
        *(float4*)&As[r][c4] = v;
    }
    __syncthreads();

    int tx = tid & 31, ty = tid >> 5;
    int c0 = tx * 4, r0 = ty * 4;
    float acc[4][4] = {};

    for (int k = 0; k < F; k += 4) {
        float4 a4[4];
#pragma unroll
        for (int i = 0; i < 4; ++i) a4[i] = *(const float4*)&As[r0 + i][k];
#pragma unroll
        for (int u = 0; u < 4; ++u) {
            float4 w = *(const float4*)(W + (size_t)(k + u) * F + c0);
#pragma unroll
            for (int i = 0; i < 4; ++i) {
                float a = (u == 0) ? a4[i].x : (u == 1) ? a4[i].y : (u == 2) ? a4[i].z : a4[i].w;
                acc[i][0] += a * w.x;
                acc[i][1] += a * w.y;
                acc[i][2] += a * w.z;
                acc[i][3] += a * w.w;
            }
        }
    }

#pragma unroll
    for (int i = 0; i < 4; ++i) {
        float4 o;
        o.x = acc[i][0]; o.y = acc[i][1]; o.z = acc[i][2]; o.w = acc[i][3];
        *(float4*)(C + (size_t)(row0 + r0 + i) * F + c0) = o;
    }
}

// ---------------------------------------------------------------------------
// Gather + bias + relu: out[n] = relu(mean_{j in nbrs(n)} y[j] + b).
// One wave per node. Pair-gather: half = lane>>5 picks even/odd neighbor,
// sub = lane&31 is the float4 column -> each instr moves 2 rows (1 KB),
// 8 gathers in flight. Butterfly shfl (lane^32) merges halves.
// ---------------------------------------------------------------------------
__global__ __launch_bounds__(256)
void agg_bias_relu_kernel(const float* __restrict__ y, const int* __restrict__ cnt,
                          const int* __restrict__ bucket, const float* __restrict__ b,
                          float* __restrict__ out) {
    int wid  = (blockIdx.x * blockDim.x + threadIdx.x) >> 6;
    int lane = threadIdx.x & 63;
    if (wid >= N_NODES) return;
    int half = lane >> 5;
    int sub  = lane & 31;
    int deg  = cnt[wid];
    const int* lst = bucket + (size_t)wid * CAP;
    const float4* f4 = (const float4*)y;

    float4 acc; acc.x = acc.y = acc.z = acc.w = 0.f;
    int j = 0;
    for (; j + 16 <= deg; j += 16) {
        int4 ia = *(const int4*)(lst + j);
        int4 ib = *(const int4*)(lst + j + 4);
        int4 ic = *(const int4*)(lst + j + 8);
        int4 id = *(const int4*)(lst + j + 12);
        int i0 = half ? ia.y : ia.x;
        int i1 = half ? ia.w : ia.z;
        int i2 = half ? ib.y : ib.x;
        int i3 = half ? ib.w : ib.z;
        int i4 = half ? ic.y : ic.x;
        int i5 = half ? ic.w : ic.z;
        int i6 = half ? id.y : id.x;
        int i7 = half ? id.w : id.z;
        float4 v0 = f4[(size_t)i0 * 32 + sub];
        float4 v1 = f4[(size_t)i1 * 32 + sub];
        float4 v2 = f4[(size_t)i2 * 32 + sub];
        float4 v3 = f4[(size_t)i3 * 32 + sub];
        float4 v4 = f4[(size_t)i4 * 32 + sub];
        float4 v5 = f4[(size_t)i5 * 32 + sub];
        float4 v6 = f4[(size_t)i6 * 32 + sub];
        float4 v7 = f4[(size_t)i7 * 32 + sub];
        acc.x += ((v0.x + v1.x) + (v2.x + v3.x)) + ((v4.x + v5.x) + (v6.x + v7.x));
        acc.y += ((v0.y + v1.y) + (v2.y + v3.y)) + ((v4.y + v5.y) + (v6.y + v7.y));
        acc.z += ((v0.z + v1.z) + (v2.z + v3.z)) + ((v4.z + v5.z) + (v6.z + v7.z));
        acc.w += ((v0.w + v1.w) + (v2.w + v3.w)) + ((v4.w + v5.w) + (v6.w + v7.w));
    }
    for (; j + 2 <= deg; j += 2) {
        int2 ii = *(const int2*)(lst + j);
        int idx = half ? ii.y : ii.x;
        float4 v = f4[(size_t)idx * 32 + sub];
        acc.x += v.x; acc.y += v.y; acc.z += v.z; acc.w += v.w;
    }
    if (j < deg && half == 0) {
        float4 v = f4[(size_t)lst[j] * 32 + sub];
        acc.x += v.x; acc.y += v.y; acc.z += v.z; acc.w += v.w;
    }
    acc.x += __shfl(acc.x, lane ^ 32);
    acc.y += __shfl(acc.y, lane ^ 32);
    acc.z += __shfl(acc.z, lane ^ 32);
    acc.w += __shfl(acc.w, lane ^ 32);

    if (half == 0) {
        float inv = 1.0f / fmaxf((float)deg, 1.0f);
        float4 bv = ((const float4*)b)[sub];
        float4 o;
        o.x = fmaxf(acc.x * inv + bv.x, 0.f);
        o.y = fmaxf(acc.y * inv + bv.y, 0.f);
        o.z = fmaxf(acc.z * inv + bv.z, 0.f);
        o.w = fmaxf(acc.w * inv + bv.w, 0.f);
        ((float4*)out)[(size_t)wid * 32 + sub] = o;
    }
}

// ---------------------------------------------------------------------------
// Last layer: out2[n] = relu(mean(y2) + b2) @ W3 + b3   (2 output cols).
// Same gather as above; epilogue does the 128->2 dot via width-32 reduce.
// ---------------------------------------------------------------------------
__global__ __launch_bounds__(256)
void agg_final_kernel(const float* __restrict__ y, const int* __restrict__ cnt,
                      const int* __restrict__ bucket, const float* __restrict__ b,
                      const float* __restrict__ W3, const float* __restrict__ b3,
                      float* __restrict__ out) {
    int wid  = (blockIdx.x * blockDim.x + threadIdx.x) >> 6;
    int lane = threadIdx.x & 63;
    if (wid >= N_NODES) return;
    int half = lane >> 5;
    int sub  = lane & 31;
    int deg  = cnt[wid];
    const int* lst = bucket + (size_t)wid * CAP;
    const float4* f4 = (const float4*)y;

    float4 acc; acc.x = acc.y = acc.z = acc.w = 0.f;
    int j = 0;
    for (; j + 16 <= deg; j += 16) {
        int4 ia = *(const int4*)(lst + j);
        int4 ib = *(const int4*)(lst + j + 4);
        int4 ic = *(const int4*)(lst + j + 8);
        int4 id = *(const int4*)(lst + j + 12);
        int i0 = half ? ia.y : ia.x;
        int i1 = half ? ia.w : ia.z;
        int i2 = half ? ib.y : ib.x;
        int i3 = half ? ib.w : ib.z;
        int i4 = half ? ic.y : ic.x;
        int i5 = half ? ic.w : ic.z;
        int i6 = half ? id.y : id.x;
        int i7 = half ? id.w : id.z;
        float4 v0 = f4[(size_t)i0 * 32 + sub];
        float4 v1 = f4[(size_t)i1 * 32 + sub];
        float4 v2 = f4[(size_t)i2 * 32 + sub];
        float4 v3 = f4[(size_t)i3 * 32 + sub];
        float4 v4 = f4[(size_t)i4 * 32 + sub];
        float4 v5 = f4[(size_t)i5 * 32 + sub];
        float4 v6 = f4[(size_t)i6 * 32 + sub];
        float4 v7 = f4[(size_t)i7 * 32 + sub];
        acc.x += ((v0.x + v1.x) + (v2.x + v3.x)) + ((v4.x + v5.x) + (v6.x + v7.x));
        acc.y += ((v0.y + v1.y) + (v2.y + v3.y)) + ((v4.y + v5.y) + (v6.y + v7.y));
        acc.z += ((v0.z + v1.z) + (v2.z + v3.z)) + ((v4.z + v5.z) + (v6.z + v7.z));
        acc.w += ((v0.w + v1.w) + (v2.w + v3.w)) + ((v4.w + v5.w) + (v6.w + v7.w));
    }
    for (; j + 2 <= deg; j += 2) {
        int2 ii = *(const int2*)(lst + j);
        int idx = half ? ii.y : ii.x;
        float4 v = f4[(size_t)idx * 32 + sub];
        acc.x += v.x; acc.y += v.y; acc.z += v.z; acc.w += v.w;
    }
    if (j < deg && half == 0) {
        float4 v = f4[(size_t)lst[j] * 32 + sub];
        acc.x += v.x; acc.y += v.y; acc.z += v.z; acc.w += v.w;
    }
    acc.x += __shfl(acc.x, lane ^ 32);
    acc.y += __shfl(acc.y, lane ^ 32);
    acc.z += __shfl(acc.z, lane ^ 32);
    acc.w += __shfl(acc.w, lane ^ 32);

    // both halves now hold the full column sums for cols sub*4..sub*4+3
    float inv = 1.0f / fmaxf((float)deg, 1.0f);
    float4 bv = ((const float4*)b)[sub];
    float h0 = fmaxf(acc.x * inv + bv.x, 0.f);
    float h1 = fmaxf(acc.y * inv + bv.y, 0.f);
    float h2 = fmaxf(acc.z * inv + bv.z, 0.f);
    float h3 = fmaxf(acc.w * inv + bv.w, 0.f);
    float2 w0 = ((const float2*)W3)[sub * 4];
    float2 w1 = ((const float2*)W3)[sub * 4 + 1];
    float2 w2 = ((const float2*)W3)[sub * 4 + 2];
    float2 w3 = ((const float2*)W3)[sub * 4 + 3];
    float p0 = h0 * w0.x + h1 * w1.x + h2 * w2.x + h3 * w3.x;
    float p1 = h0 * w0.y + h1 * w1.y + h2 * w2.y + h3 * w3.y;
#pragma unroll
    for (int off = 16; off > 0; off >>= 1) {
        p0 += __shfl_down(p0, off, 32);
        p1 += __shfl_down(p1, off, 32);
    }
    if (lane == 0) {
        float2 o; o.x = p0 + b3[0]; o.y = p1 + b3[1];
        *(float2*)(out + (size_t)wid * 2) = o;
    }
}

// ---------------------------------------------------------------------------
extern "C" void kernel_launch(void* const* d_in, const int* in_sizes, int n_in,
                              void* d_out, int out_size, void* d_ws, size_t ws_size,
                              hipStream_t stream) {
    const float* x   = (const float*)d_in[0];
    const int*   ei  = (const int*)d_in[1];
    const int*   src = ei;
    const int*   dst = ei + N_EDGES;
    const float* W1 = (const float*)d_in[2];
    const float* b1 = (const float*)d_in[3];
    const float* W2 = (const float*)d_in[4];
    const float* b2 = (const float*)d_in[5];
    const float* W3 = (const float*)d_in[6];
    const float* b3 = (const float*)d_in[7];
    float* out = (float*)d_out;

    char* base = (char*)d_ws;
    size_t off = 0;
    auto take = [&](size_t bytes) -> char* {
        char* p = base + off;
        off += (bytes + 255) & ~(size_t)255;
        return p;
    };
    int*   cnt    = (int*)  take(N_NODES * sizeof(int));
    int*   bucket = (int*)  take((size_t)N_NODES * CAP * sizeof(int));
    float* y      = (float*)take((size_t)N_NODES * F * sizeof(float));  // GEMM output
    float* h      = (float*)take((size_t)N_NODES * F * sizeof(float));  // post-agg hidden

    hipMemsetAsync(cnt, 0, N_NODES * sizeof(int), stream);
    bucket_kernel<<<(N_EDGES + 255) / 256, 256, 0, stream>>>(src, dst, cnt, bucket);

    // layer 1 (GEMM first; mean is linear): y = x @ W1; h = relu(mean(y) + b1)
    gemm_kernel<<<N_NODES / 32, 256, 0, stream>>>(x, W1, y);
    agg_bias_relu_kernel<<<(N_NODES * 64) / 256, 256, 0, stream>>>(y, cnt, bucket, b1, h);
    // layer 2: y = h @ W2; out = relu(mean(y) + b2) @ W3 + b3  (proj fused)
    gemm_kernel<<<N_NODES / 32, 256, 0, stream>>>(h, W2, y);
    agg_final_kernel<<<(N_NODES * 64) / 256, 256, 0, stream>>>(y, cnt, bucket, b2, W3, b3, out);
}

// Round 7
// 212.977 us; speedup vs baseline: 1.0660x; 1.0104x over previous
//
#include <hip/hip_runtime.h>

#define N_NODES 20000
#define N_EDGES 640000
#define F 128
#define CAP 128          // max in-degree; deg ~ Binomial(640K, 1/20K), P(deg>=128) ~ 1e-37
#define GEMM_BLOCKS (N_NODES / 32)     // 625
#define BUCKET_BLOCKS (N_EDGES / 256)  // 2500

// HISTORY:
//  r2/r3: fused GEMM+proj epilogue spilled (64-VGPR cap, then VGPR=256 + 565 MB scratch).
//  r4: de-fused, no spill: 218 us. r5: gather-into-GEMM-tile fusion dropped grid to 625
//      blocks -> occupancy 22.6%, latency-bound: 227 us (reverted).
//  r6: linearity of mean (mean(x)@W == mean(x@W)): GEMM first, standalone gather with
//      bias/relu/proj in epilogue: 215 us, absmax 8x better.
//  r7: (a) bucket+gemm1 are independent -> merged into one grid-split kernel (overlap);
//      (b) agg gets 2 waves per node (2x loads in flight), LDS combine.

// ---------------------------------------------------------------------------
// 16-neighbor pair-gather step: half = lane>>5 picks even/odd member of each
// index pair, sub = lane&31 is the float4 column. 8 x 1KB loads in flight.
// ---------------------------------------------------------------------------
__device__ __forceinline__ void gather16(const float4* __restrict__ f4,
                                         const int* __restrict__ lst, int j,
                                         int half, int sub, float4& acc) {
    int4 ia = *(const int4*)(lst + j);
    int4 ib = *(const int4*)(lst + j + 4);
    int4 ic = *(const int4*)(lst + j + 8);
    int4 id = *(const int4*)(lst + j + 12);
    int i0 = half ? ia.y : ia.x;
    int i1 = half ? ia.w : ia.z;
    int i2 = half ? ib.y : ib.x;
    int i3 = half ? ib.w : ib.z;
    int i4 = half ? ic.y : ic.x;
    int i5 = half ? ic.w : ic.z;
    int i6 = half ? id.y : id.x;
    int i7 = half ? id.w : id.z;
    float4 v0 = f4[(size_t)i0 * 32 + sub];
    float4 v1 = f4[(size_t)i1 * 32 + sub];
    float4 v2 = f4[(size_t)i2 * 32 + sub];
    float4 v3 = f4[(size_t)i3 * 32 + sub];
    float4 v4 = f4[(size_t)i4 * 32 + sub];
    float4 v5 = f4[(size_t)i5 * 32 + sub];
    float4 v6 = f4[(size_t)i6 * 32 + sub];
    float4 v7 = f4[(size_t)i7 * 32 + sub];
    acc.x += ((v0.x + v1.x) + (v2.x + v3.x)) + ((v4.x + v5.x) + (v6.x + v7.x));
    acc.y += ((v0.y + v1.y) + (v2.y + v3.y)) + ((v4.y + v5.y) + (v6.y + v7.y));
    acc.z += ((v0.z + v1.z) + (v2.z + v3.z)) + ((v4.z + v5.z) + (v6.z + v7.z));
    acc.w += ((v0.w + v1.w) + (v2.w + v3.w)) + ((v4.w + v5.w) + (v6.w + v7.w));
}

// Per-wave half-aggregation over chunks c = wh, wh+2, ... of 16 neighbors;
// the tail (deg & 15) belongs to wave (nfull & 1). Returns pair-merged acc.
__device__ __forceinline__ float4 wave_gather(const float4* __restrict__ f4,
                                              const int* __restrict__ lst, int deg,
                                              int wh, int half, int sub, int lane) {
    float4 acc; acc.x = acc.y = acc.z = acc.w = 0.f;
    int nfull = deg >> 4;
    for (int c = wh; c < nfull; c += 2)
        gather16(f4, lst, c << 4, half, sub, acc);
    if (wh == (nfull & 1)) {
        int j = nfull << 4;
        for (; j + 2 <= deg; j += 2) {
            int2 ii = *(const int2*)(lst + j);
            int idx = half ? ii.y : ii.x;
            float4 v = f4[(size_t)idx * 32 + sub];
            acc.x += v.x; acc.y += v.y; acc.z += v.z; acc.w += v.w;
        }
        if (j < deg && half == 0) {
            float4 v = f4[(size_t)lst[j] * 32 + sub];
            acc.x += v.x; acc.y += v.y; acc.z += v.z; acc.w += v.w;
        }
    }
    // merge even/odd-neighbor halves (lane ^ 32)
    acc.x += __shfl(acc.x, lane ^ 32);
    acc.y += __shfl(acc.y, lane ^ 32);
    acc.z += __shfl(acc.z, lane ^ 32);
    acc.w += __shfl(acc.w, lane ^ 32);
    return acc;
}

// ---------------------------------------------------------------------------
// Merged kernel: blocks [0, GEMM_BLOCKS) compute y = A @ W (32-row tile,
// proven 44-VGPR structure); blocks [GEMM_BLOCKS, +BUCKET_BLOCKS) scatter the
// edge list into per-destination buckets. No data dependency between halves.
// ---------------------------------------------------------------------------
__global__ __launch_bounds__(256)
void gemm_bucket_kernel(const float* __restrict__ A, const float* __restrict__ W,
                        float* __restrict__ C,
                        const int* __restrict__ src, const int* __restrict__ dst,
                        int* __restrict__ cnt, int* __restrict__ bucket) {
    __shared__ float As[32][F + 4];
    int tid = threadIdx.x;

    if (blockIdx.x >= GEMM_BLOCKS) {
        int e = (blockIdx.x - GEMM_BLOCKS) * 256 + tid;
        if (e < N_EDGES) {
            int d = dst[e];
            int pos = atomicAdd(&cnt[d], 1);
            if (pos < CAP) bucket[(size_t)d * CAP + pos] = src[e];
        }
        return;
    }

    int row0 = blockIdx.x * 32;
    const float4* A4 = (const float4*)(A + (size_t)row0 * F);
    for (int i = tid; i < 32 * 32; i += 256) {
        float4 v = A4[i];
        int r = i >> 5, c4 = (i & 31) * 4;
        *(float4*)&As[r][c4] = v;
    }
    __syncthreads();

    int tx = tid & 31, ty = tid >> 5;
    int c0 = tx * 4, r0 = ty * 4;
    float acc[4][4] = {};

    for (int k = 0; k < F; k += 4) {
        float4 a4[4];
#pragma unroll
        for (int i = 0; i < 4; ++i) a4[i] = *(const float4*)&As[r0 + i][k];
#pragma unroll
        for (int u = 0; u < 4; ++u) {
            float4 w = *(const float4*)(W + (size_t)(k + u) * F + c0);
#pragma unroll
            for (int i = 0; i < 4; ++i) {
                float a = (u == 0) ? a4[i].x : (u == 1) ? a4[i].y : (u == 2) ? a4[i].z : a4[i].w;
                acc[i][0] += a * w.x;
                acc[i][1] += a * w.y;
                acc[i][2] += a * w.z;
                acc[i][3] += a * w.w;
            }
        }
    }

#pragma unroll
    for (int i = 0; i < 4; ++i) {
        float4 o;
        o.x = acc[i][0]; o.y = acc[i][1]; o.z = acc[i][2]; o.w = acc[i][3];
        *(float4*)(C + (size_t)(row0 + r0 + i) * F + c0) = o;
    }
}

// ---------------------------------------------------------------------------
// Plain GEMM (layer 2): C = A @ W.
// ---------------------------------------------------------------------------
__global__ __launch_bounds__(256)
void gemm_kernel(const float* __restrict__ A, const float* __restrict__ W,
                 float* __restrict__ C) {
    __shared__ float As[32][F + 4];
    int tid  = threadIdx.x;
    int row0 = blockIdx.x * 32;

    const float4* A4 = (const float4*)(A + (size_t)row0 * F);
    for (int i = tid; i < 32 * 32; i += 256) {
        float4 v = A4[i];
        int r = i >> 5, c4 = (i & 31) * 4;
        *(float4*)&As[r][c4] = v;
    }
    __syncthreads();

    int tx = tid & 31, ty = tid >> 5;
    int c0 = tx * 4, r0 = ty * 4;
    float acc[4][4] = {};

    for (int k = 0; k < F; k += 4) {
        float4 a4[4];
#pragma unroll
        for (int i = 0; i < 4; ++i) a4[i] = *(const float4*)&As[r0 + i][k];
#pragma unroll
        for (int u = 0; u < 4; ++u) {
            float4 w = *(const float4*)(W + (size_t)(k + u) * F + c0);
#pragma unroll
            for (int i = 0; i < 4; ++i) {
                float a = (u == 0) ? a4[i].x : (u == 1) ? a4[i].y : (u == 2) ? a4[i].z : a4[i].w;
                acc[i][0] += a * w.x;
                acc[i][1] += a * w.y;
                acc[i][2] += a * w.z;
                acc[i][3] += a * w.w;
            }
        }
    }

#pragma unroll
    for (int i = 0; i < 4; ++i) {
        float4 o;
        o.x = acc[i][0]; o.y = acc[i][1]; o.z = acc[i][2]; o.w = acc[i][3];
        *(float4*)(C + (size_t)(row0 + r0 + i) * F + c0) = o;
    }
}

// ---------------------------------------------------------------------------
// Gather + bias + relu, 2 waves per node (2x loads in flight vs r6).
// Block = 256 thr = 4 waves = 2 nodes. Wave wh in {0,1} takes 16-neighbor
// chunks round-robin; partials combined through LDS.
// ---------------------------------------------------------------------------
__global__ __launch_bounds__(256)
void agg_bias_relu_kernel(const float* __restrict__ y, const int* __restrict__ cnt,
                          const int* __restrict__ bucket, const float* __restrict__ b,
                          float* __restrict__ out) {
    __shared__ float4 part[2][32];
    int tid  = threadIdx.x;
    int wave = tid >> 6, lane = tid & 63;
    int nl   = wave >> 1;          // node within block
    int wh   = wave & 1;           // neighbor-list half
    int node = blockIdx.x * 2 + nl;
    int half = lane >> 5, sub = lane & 31;
    int deg  = cnt[node];
    const int* lst = bucket + (size_t)node * CAP;
    const float4* f4 = (const float4*)y;

    float4 acc = wave_gather(f4, lst, deg, wh, half, sub, lane);

    if (wh == 1 && half == 0) part[nl][sub] = acc;
    __syncthreads();
    if (wh == 0 && half == 0) {
        float4 p = part[nl][sub];
        float inv = 1.0f / fmaxf((float)deg, 1.0f);
        float4 bv = ((const float4*)b)[sub];
        float4 o;
        o.x = fmaxf((acc.x + p.x) * inv + bv.x, 0.f);
        o.y = fmaxf((acc.y + p.y) * inv + bv.y, 0.f);
        o.z = fmaxf((acc.z + p.z) * inv + bv.z, 0.f);
        o.w = fmaxf((acc.w + p.w) * inv + bv.w, 0.f);
        ((float4*)out)[(size_t)node * 32 + sub] = o;
    }
}

// ---------------------------------------------------------------------------
// Last layer: out[n] = relu(mean(y)[n] + b2) @ W3 + b3 (2 cols). Same 2-wave
// gather; epilogue dot + width-32 shuffle reduce on wave 0.
// ---------------------------------------------------------------------------
__global__ __launch_bounds__(256)
void agg_final_kernel(const float* __restrict__ y, const int* __restrict__ cnt,
                      const int* __restrict__ bucket, const float* __restrict__ b,
                      const float* __restrict__ W3, const float* __restrict__ b3,
                      float* __restrict__ out) {
    __shared__ float4 part[2][32];
    int tid  = threadIdx.x;
    int wave = tid >> 6, lane = tid & 63;
    int nl   = wave >> 1;
    int wh   = wave & 1;
    int node = blockIdx.x * 2 + nl;
    int half = lane >> 5, sub = lane & 31;
    int deg  = cnt[node];
    const int* lst = bucket + (size_t)node * CAP;
    const float4* f4 = (const float4*)y;

    float4 acc = wave_gather(f4, lst, deg, wh, half, sub, lane);

    if (wh == 1 && half == 0) part[nl][sub] = acc;
    __syncthreads();
    if (wh == 0 && half == 0) {
        float4 p = part[nl][sub];
        float inv = 1.0f / fmaxf((float)deg, 1.0f);
        float4 bv = ((const float4*)b)[sub];
        float h0 = fmaxf((acc.x + p.x) * inv + bv.x, 0.f);
        float h1 = fmaxf((acc.y + p.y) * inv + bv.y, 0.f);
        float h2 = fmaxf((acc.z + p.z) * inv + bv.z, 0.f);
        float h3 = fmaxf((acc.w + p.w) * inv + bv.w, 0.f);
        float2 w0 = ((const float2*)W3)[sub * 4];
        float2 w1 = ((const float2*)W3)[sub * 4 + 1];
        float2 w2 = ((const float2*)W3)[sub * 4 + 2];
        float2 w3 = ((const float2*)W3)[sub * 4 + 3];
        float p0 = h0 * w0.x + h1 * w1.x + h2 * w2.x + h3 * w3.x;
        float p1 = h0 * w0.y + h1 * w1.y + h2 * w2.y + h3 * w3.y;
#pragma unroll
        for (int off = 16; off > 0; off >>= 1) {
            p0 += __shfl_down(p0, off, 32);
            p1 += __shfl_down(p1, off, 32);
        }
        if (sub == 0) {
            float2 o; o.x = p0 + b3[0]; o.y = p1 + b3[1];
            *(float2*)(out + (size_t)node * 2) = o;
        }
    }
}

// ---------------------------------------------------------------------------
extern "C" void kernel_launch(void* const* d_in, const int* in_sizes, int n_in,
                              void* d_out, int out_size, void* d_ws, size_t ws_size,
                              hipStream_t stream) {
    const float* x   = (const float*)d_in[0];
    const int*   ei  = (const int*)d_in[1];
    const int*   src = ei;
    const int*   dst = ei + N_EDGES;
    const float* W1 = (const float*)d_in[2];
    const float* b1 = (const float*)d_in[3];
    const float* W2 = (const float*)d_in[4];
    const float* b2 = (const float*)d_in[5];
    const float* W3 = (const float*)d_in[6];
    const float* b3 = (const float*)d_in[7];
    float* out = (float*)d_out;

    char* base = (char*)d_ws;
    size_t off = 0;
    auto take = [&](size_t bytes) -> char* {
        char* p = base + off;
        off += (bytes + 255) & ~(size_t)255;
        return p;
    };
    int*   cnt    = (int*)  take(N_NODES * sizeof(int));
    int*   bucket = (int*)  take((size_t)N_NODES * CAP * sizeof(int));
    float* y      = (float*)take((size_t)N_NODES * F * sizeof(float));
    float* h      = (float*)take((size_t)N_NODES * F * sizeof(float));

    hipMemsetAsync(cnt, 0, N_NODES * sizeof(int), stream);

    // layer 1 GEMM (y = x@W1) and bucket build overlap in one grid
    gemm_bucket_kernel<<<GEMM_BLOCKS + BUCKET_BLOCKS, 256, 0, stream>>>(
        x, W1, y, src, dst, cnt, bucket);
    // h = relu(mean(y) + b1)
    agg_bias_relu_kernel<<<N_NODES / 2, 256, 0, stream>>>(y, cnt, bucket, b1, h);
    // y = h @ W2
    gemm_kernel<<<N_NODES / 32, 256, 0, stream>>>(h, W2, y);
    // out = relu(mean(y) + b2) @ W3 + b3
    agg_final_kernel<<<N_NODES / 2, 256, 0, stream>>>(y, cnt, bucket, b2, W3, b3, out);
}

// Round 8
// 203.059 us; speedup vs baseline: 1.1181x; 1.0488x over previous
//
#include <hip/hip_runtime.h>

#define N_NODES 20000
#define N_EDGES 640000
#define F 128
#define CAP 128          // max in-degree; deg ~ Binomial(640K, 1/20K), P(deg>=128) ~ 1e-37
#define GEMM_BLOCKS (N_NODES / 32)     // 625
#define BUCKET_BLOCKS (N_EDGES / 256)  // 2500

// HISTORY:
//  r2/r3: fused GEMM+proj epilogue spilled (64-VGPR cap; VGPR=256 + 565 MB scratch).
//  r4: de-fused: 218 us. r5: gather-into-GEMM fusion -> 625 blocks, occ 22.6%: 227 (revert).
//  r6: mean-linearity reorder (GEMM first): 215 us. r7: gemm1+bucket merged, 2-wave agg:
//      213 us; bucket scatter shows 48 MB write-amp, aggs ~40+ us with ~100 MB L2-miss fetch.
//  r8: (a) uint16 bucket (node ids < 65536): halves scatter footprint+amplification.
//      (b) slice-partitioned agg: 4 feature-slices x 32 floats (2.56 MB, fits 4 MB XCD L2),
//          blockIdx%8 XCD swizzle pins each slice to its XCD's L2 -> gather = L2 hits.

// ---------------------------------------------------------------------------
// Merged: blocks [0,625) y = A @ W (proven 44-VGPR tile); blocks [625,3125)
// scatter edges into per-destination uint16 buckets. Independent halves.
// ---------------------------------------------------------------------------
__global__ __launch_bounds__(256)
void gemm_bucket_kernel(const float* __restrict__ A, const float* __restrict__ W,
                        float* __restrict__ C,
                        const int* __restrict__ src, const int* __restrict__ dst,
                        int* __restrict__ cnt, unsigned short* __restrict__ bucket) {
    __shared__ float As[32][F + 4];
    int tid = threadIdx.x;

    if (blockIdx.x >= GEMM_BLOCKS) {
        int e = (blockIdx.x - GEMM_BLOCKS) * 256 + tid;
        if (e < N_EDGES) {
            int d = dst[e];
            int pos = atomicAdd(&cnt[d], 1);
            if (pos < CAP) bucket[(size_t)d * CAP + pos] = (unsigned short)src[e];
        }
        return;
    }

    int row0 = blockIdx.x * 32;
    const float4* A4 = (const float4*)(A + (size_t)row0 * F);
    for (int i = tid; i < 32 * 32; i += 256) {
        float4 v = A4[i];
        int r = i >> 5, c4 = (i & 31) * 4;
        *(float4*)&As[r][c4] = v;
    }
    __syncthreads();

    int tx = tid & 31, ty = tid >> 5;
    int c0 = tx * 4, r0 = ty * 4;
    float acc[4][4] = {};

    for (int k = 0; k < F; k += 4) {
        float4 a4[4];
#pragma unroll
        for (int i = 0; i < 4; ++i) a4[i] = *(const float4*)&As[r0 + i][k];
#pragma unroll
        for (int u = 0; u < 4; ++u) {
            float4 w = *(const float4*)(W + (size_t)(k + u) * F + c0);
#pragma unroll
            for (int i = 0; i < 4; ++i) {
                float a = (u == 0) ? a4[i].x : (u == 1) ? a4[i].y : (u == 2) ? a4[i].z : a4[i].w;
                acc[i][0] += a * w.x;
                acc[i][1] += a * w.y;
                acc[i][2] += a * w.z;
                acc[i][3] += a * w.w;
            }
        }
    }

#pragma unroll
    for (int i = 0; i < 4; ++i) {
        float4 o;
        o.x = acc[i][0]; o.y = acc[i][1]; o.z = acc[i][2]; o.w = acc[i][3];
        *(float4*)(C + (size_t)(row0 + r0 + i) * F + c0) = o;
    }
}

// ---------------------------------------------------------------------------
// Plain GEMM (layer 2): C = A @ W.
// ---------------------------------------------------------------------------
__global__ __launch_bounds__(256)
void gemm_kernel(const float* __restrict__ A, const float* __restrict__ W,
                 float* __restrict__ C) {
    __shared__ float As[32][F + 4];
    int tid  = threadIdx.x;
    int row0 = blockIdx.x * 32;

    const float4* A4 = (const float4*)(A + (size_t)row0 * F);
    for (int i = tid; i < 32 * 32; i += 256) {
        float4 v = A4[i];
        int r = i >> 5, c4 = (i & 31) * 4;
        *(float4*)&As[r][c4] = v;
    }
    __syncthreads();

    int tx = tid & 31, ty = tid >> 5;
    int c0 = tx * 4, r0 = ty * 4;
    float acc[4][4] = {};

    for (int k = 0; k < F; k += 4) {
        float4 a4[4];
#pragma unroll
        for (int i = 0; i < 4; ++i) a4[i] = *(const float4*)&As[r0 + i][k];
#pragma unroll
        for (int u = 0; u < 4; ++u) {
            float4 w = *(const float4*)(W + (size_t)(k + u) * F + c0);
#pragma unroll
            for (int i = 0; i < 4; ++i) {
                float a = (u == 0) ? a4[i].x : (u == 1) ? a4[i].y : (u == 2) ? a4[i].z : a4[i].w;
                acc[i][0] += a * w.x;
                acc[i][1] += a * w.y;
                acc[i][2] += a * w.z;
                acc[i][3] += a * w.w;
            }
        }
    }

#pragma unroll
    for (int i = 0; i < 4; ++i) {
        float4 o;
        o.x = acc[i][0]; o.y = acc[i][1]; o.z = acc[i][2]; o.w = acc[i][3];
        *(float4*)(C + (size_t)(row0 + r0 + i) * F + c0) = o;
    }
}

// ---------------------------------------------------------------------------
// Slice-partitioned gather + bias + relu:
//   out[n, slice] = relu(mean_{j in nbrs(n)} y[j, slice] + b[slice])
// Grid 20000 blocks x 256. XCD swizzle: g = bid%8 picks the XCD (heuristic);
// slice = g&3 -> each XCD's L2 only caches one 2.56 MB y-slice (fits 4 MB L2).
// Wave = 8 neighbor-rows x 8 float4-cols: one gather instr = 8 rows x 128 B.
// 4 chunks (32 neighbors) unrolled -> 4 gathers in flight. shfl_xor reduce.
// ---------------------------------------------------------------------------
__global__ __launch_bounds__(256)
void slice_agg_kernel(const float* __restrict__ y, const int* __restrict__ cnt,
                      const unsigned short* __restrict__ bucket,
                      const float* __restrict__ b, float* __restrict__ out) {
    int bid   = blockIdx.x;
    int g     = bid & 7;        // XCD group (dispatch heuristic)
    int i     = bid >> 3;       // 0..2499 within group
    int slice = g & 3;          // 2 groups (XCDs) per slice
    int j     = i * 2 + (g >> 2);   // 0..4999 block-within-slice
    int wave  = threadIdx.x >> 6;
    int lane  = threadIdx.x & 63;
    int node  = j * 4 + wave;
    int r     = lane >> 3;      // neighbor row 0..7
    int c4    = lane & 7;       // float4 col within slice

    int deg = cnt[node];
    const unsigned short* lst = bucket + (size_t)node * CAP;
    const float4* f4 = (const float4*)y + slice * 8 + c4;   // row stride 32 float4

    float4 acc; acc.x = acc.y = acc.z = acc.w = 0.f;
    int nfull = deg >> 3;       // full 8-neighbor chunks
    int c = 0;
    for (; c + 4 <= nfull; c += 4) {
        int base = (c << 3) + r;
        int i0 = lst[base];
        int i1 = lst[base + 8];
        int i2 = lst[base + 16];
        int i3 = lst[base + 24];
        float4 v0 = f4[(size_t)i0 * 32];
        float4 v1 = f4[(size_t)i1 * 32];
        float4 v2 = f4[(size_t)i2 * 32];
        float4 v3 = f4[(size_t)i3 * 32];
        acc.x += (v0.x + v1.x) + (v2.x + v3.x);
        acc.y += (v0.y + v1.y) + (v2.y + v3.y);
        acc.z += (v0.z + v1.z) + (v2.z + v3.z);
        acc.w += (v0.w + v1.w) + (v2.w + v3.w);
    }
    for (; c < nfull; ++c) {
        int idx = lst[(c << 3) + r];
        float4 v = f4[(size_t)idx * 32];
        acc.x += v.x; acc.y += v.y; acc.z += v.z; acc.w += v.w;
    }
    if (r < (deg & 7)) {        // tail neighbors
        int idx = lst[(nfull << 3) + r];
        float4 v = f4[(size_t)idx * 32];
        acc.x += v.x; acc.y += v.y; acc.z += v.z; acc.w += v.w;
    }

    // reduce across the 8 row-groups (lanes r=0..7 hold disjoint neighbors)
#pragma unroll
    for (int off = 8; off < 64; off <<= 1) {
        acc.x += __shfl_xor(acc.x, off);
        acc.y += __shfl_xor(acc.y, off);
        acc.z += __shfl_xor(acc.z, off);
        acc.w += __shfl_xor(acc.w, off);
    }

    if (r == 0) {   // lane == c4
        float inv = 1.0f / fmaxf((float)deg, 1.0f);
        float4 bv = ((const float4*)b)[slice * 8 + c4];
        float4 o;
        o.x = fmaxf(acc.x * inv + bv.x, 0.f);
        o.y = fmaxf(acc.y * inv + bv.y, 0.f);
        o.z = fmaxf(acc.z * inv + bv.z, 0.f);
        o.w = fmaxf(acc.w * inv + bv.w, 0.f);
        ((float4*)out)[(size_t)node * 32 + slice * 8 + c4] = o;
    }
}

// ---------------------------------------------------------------------------
// out[N x 2] = h[N x 128] @ W3[128 x 2] + b3. One wave per node, shuffle
// reduce. Proven cheap (never in any top-5).
// ---------------------------------------------------------------------------
__global__ __launch_bounds__(256)
void final_kernel(const float* __restrict__ h, const float* __restrict__ W3,
                  const float* __restrict__ b3, float* __restrict__ out) {
    int wid  = (blockIdx.x * blockDim.x + threadIdx.x) >> 6;
    int lane = threadIdx.x & 63;
    if (wid >= N_NODES) return;
    float2 v = ((const float2*)h)[(size_t)wid * 64 + lane];
    float4 w = ((const float4*)W3)[lane];
    float a0 = v.x * w.x + v.y * w.z;
    float a1 = v.x * w.y + v.y * w.w;
#pragma unroll
    for (int off = 32; off > 0; off >>= 1) {
        a0 += __shfl_down(a0, off);
        a1 += __shfl_down(a1, off);
    }
    if (lane == 0) {
        out[(size_t)wid * 2]     = a0 + b3[0];
        out[(size_t)wid * 2 + 1] = a1 + b3[1];
    }
}

// ---------------------------------------------------------------------------
extern "C" void kernel_launch(void* const* d_in, const int* in_sizes, int n_in,
                              void* d_out, int out_size, void* d_ws, size_t ws_size,
                              hipStream_t stream) {
    const float* x   = (const float*)d_in[0];
    const int*   ei  = (const int*)d_in[1];
    const int*   src = ei;
    const int*   dst = ei + N_EDGES;
    const float* W1 = (const float*)d_in[2];
    const float* b1 = (const float*)d_in[3];
    const float* W2 = (const float*)d_in[4];
    const float* b2 = (const float*)d_in[5];
    const float* W3 = (const float*)d_in[6];
    const float* b3 = (const float*)d_in[7];
    float* out = (float*)d_out;

    char* base = (char*)d_ws;
    size_t off = 0;
    auto take = [&](size_t bytes) -> char* {
        char* p = base + off;
        off += (bytes + 255) & ~(size_t)255;
        return p;
    };
    int*            cnt    = (int*)           take(N_NODES * sizeof(int));
    unsigned short* bucket = (unsigned short*)take((size_t)N_NODES * CAP * sizeof(unsigned short));
    float*          y      = (float*)         take((size_t)N_NODES * F * sizeof(float));
    float*          h      = (float*)         take((size_t)N_NODES * F * sizeof(float));

    hipMemsetAsync(cnt, 0, N_NODES * sizeof(int), stream);

    // layer 1 GEMM (y = x@W1) overlapped with uint16 bucket build
    gemm_bucket_kernel<<<GEMM_BLOCKS + BUCKET_BLOCKS, 256, 0, stream>>>(
        x, W1, y, src, dst, cnt, bucket);
    // h = relu(mean(y) + b1)   (slice-partitioned, XCD-L2-resident gather)
    slice_agg_kernel<<<N_NODES, 256, 0, stream>>>(y, cnt, bucket, b1, h);
    // y = h @ W2
    gemm_kernel<<<N_NODES / 32, 256, 0, stream>>>(h, W2, y);
    // h = relu(mean(y) + b2)   (reuse h; reads y only)
    slice_agg_kernel<<<N_NODES, 256, 0, stream>>>(y, cnt, bucket, b2, h);
    // out = h @ W3 + b3
    final_kernel<<<(N_NODES * 64) / 256, 256, 0, stream>>>(h, W3, b3, out);
}